// Round 5
// baseline (261.068 us; speedup 1.0000x reference)
//
#include <hip/hip_runtime.h>
#include <hip/hip_bf16.h>

typedef unsigned short u16;
typedef unsigned int u32;
using bf16x8 = __attribute__((ext_vector_type(8))) short;
using f32x4  = __attribute__((ext_vector_type(4))) float;

#define LDA   136   // 128 + 8 pad (16B-aligned rows, 2-way-max bank aliasing)
#define SLOTS 8
#define NROWS 48    // SLOTS * 6

__device__ __forceinline__ u32 pk2bf(float a, float b) {
  u32 r;
  asm("v_cvt_pk_bf16_f32 %0, %1, %2" : "=v"(r) : "v"(a), "v"(b));
  return r;
}
__device__ __forceinline__ u16 f2bf(float f) { return (u16)pk2bf(f, f); }
__device__ __forceinline__ float bf2f(u16 h) {
  union { u32 u; float f; } v; v.u = ((u32)h) << 16;
  return v.f;
}
__device__ __forceinline__ float2 bf2x2(u32 u) {
  union { u32 u; float f; } a, b; a.u = u << 16; b.u = u & 0xffff0000u;
  return make_float2(a.f, b.f);
}

#if __has_builtin(__builtin_amdgcn_exp2f)
#define EXP2F(x) __builtin_amdgcn_exp2f(x)
#else
#define EXP2F(x) exp2f(x)
#endif

#define MFMA32(a, b, c) __builtin_amdgcn_mfma_f32_16x16x32_bf16(a, b, c, 0, 0, 0)

// tanh-form GELU: x*sigmoid(x*(1.5957691 + 0.0713548*x^2)); |err vs exact erf| < 4e-4
// (numerics validated in R3/R4 runs: absmax stayed 0.0625)
__device__ __forceinline__ float gelu_f(float x) {
  const float a = x * x;
  const float b = fmaf(-0.10294538f, a, -2.3022077f);  // -log2(e)*(1.5957691+0.0713548x^2)
  const float e = EXP2F(x * b);
  return x * __builtin_amdgcn_rcpf(1.f + e);
}

// ---------------- weight convert + transpose to bf16 ----------------
// ws layout (u16): qwT[128*128] kwT vwT owT | ff1T[512*128] | ff2T[128*512]
__global__ void convert_w(const float* __restrict__ qw, const float* __restrict__ kw,
                          const float* __restrict__ vw, const float* __restrict__ ow,
                          const float* __restrict__ f1, const float* __restrict__ f2,
                          u16* __restrict__ o) {
  int i = blockIdx.x * 256 + threadIdx.x;
  if (i < 65536) {
    int which = i >> 14;
    const float* W = which == 0 ? qw : which == 1 ? kw : which == 2 ? vw : ow;
    int t = i & 16383;
    int n = t >> 7, k = t & 127;
    o[i] = f2bf(W[k * 128 + n]);
  } else if (i < 131072) {
    int t = i - 65536;
    int n = t >> 7, k = t & 127;
    o[i] = f2bf(f1[k * 512 + n]);
  } else if (i < 196608) {
    int t = i - 131072;
    int n = t >> 9, k = t & 511;
    o[i] = f2bf(f2[k * 128 + n]);
  }
}

// mfma(F1,F2): lane(l16,kg) holds D[f2row=l16][f1row=kg*4+r]
// gemm48T: Y = A(48x128) @ W; WT rows as F1 -> lane holds Y[xrow=l16][4 consecutive wcols]
__device__ __forceinline__ void gemm48T(const u16* __restrict__ A, const u16* __restrict__ WT,
                                        int ldw, f32x4 acc[3][2],
                                        int wave, int lane16, int kgrp) {
#pragma unroll
  for (int ks = 0; ks < 4; ++ks) {
    const int kk = ks * 32 + kgrp * 8;
    bf16x8 a0 = *(const bf16x8*)(A + (0 * 16 + lane16) * LDA + kk);
    bf16x8 a1 = *(const bf16x8*)(A + (1 * 16 + lane16) * LDA + kk);
    bf16x8 a2 = *(const bf16x8*)(A + (2 * 16 + lane16) * LDA + kk);
    bf16x8 b0 = *(const bf16x8*)(WT + ((wave)     * 16 + lane16) * ldw + kk);
    bf16x8 b1 = *(const bf16x8*)(WT + ((wave + 4) * 16 + lane16) * ldw + kk);
    acc[0][0] = MFMA32(b0, a0, acc[0][0]);
    acc[1][0] = MFMA32(b0, a1, acc[1][0]);
    acc[2][0] = MFMA32(b0, a2, acc[2][0]);
    acc[0][1] = MFMA32(b1, a0, acc[0][1]);
    acc[1][1] = MFMA32(b1, a1, acc[1][1]);
    acc[2][1] = MFMA32(b1, a2, acc[2][1]);
  }
}

__device__ __forceinline__ void store48T(u16* __restrict__ dst, f32x4 acc[3][2],
                                         const float* __restrict__ bias,
                                         int wave, int lane16, int kgrp) {
#pragma unroll
  for (int c = 0; c < 2; ++c) {
    const int col0 = (wave + 4 * c) * 16 + kgrp * 4;
    const float4 bv = *(const float4*)(bias + col0);
#pragma unroll
    for (int xr = 0; xr < 3; ++xr) {
      uint2 o;
      o.x = pk2bf(acc[xr][c][0] + bv.x, acc[xr][c][1] + bv.y);
      o.y = pk2bf(acc[xr][c][2] + bv.z, acc[xr][c][3] + bv.w);
      *(uint2*)(dst + (xr * 16 + lane16) * LDA + col0) = o;
    }
  }
}

__global__ __launch_bounds__(256, 4) void mitra_main(
    const float* __restrict__ x,
    const float* __restrict__ nw1, const float* __restrict__ nb1,
    const float* __restrict__ nw2, const float* __restrict__ nb2,
    const float* __restrict__ qb,  const float* __restrict__ kb,
    const float* __restrict__ vb,  const float* __restrict__ ob,
    const float* __restrict__ f1b, const float* __restrict__ f2b,
    const u16* __restrict__ wt, float* __restrict__ out) {
  __shared__ u16 XF[NROWS * LDA];   // xf -> xf2
  __shared__ u16 BA[NROWS * LDA];   // Q -> V -> H
  __shared__ u16 BB[NROWS * LDA];   // K -> O -> G
  __shared__ u16 PS[SLOTS * 2 * 36];   // softmax probs, bf16

  const int tid    = threadIdx.x;
  const int wave   = tid >> 6;
  const int lane   = tid & 63;
  const int lane16 = lane & 15;
  const int kgrp   = lane >> 4;
  const long slot0 = (long)blockIdx.x * SLOTS;

  // ---------- Phase 0: LN1(768) + LN2(128) -> XF ----------
  {
    const int s = tid >> 5, l32 = tid & 31;
    const float* xr = x + (size_t)(slot0 + s) * 768;
    float4 v[6];
    float sm = 0.f, sq = 0.f;
#pragma unroll
    for (int i = 0; i < 6; ++i) {
      v[i] = *(const float4*)(xr + (l32 + 32 * i) * 4);
      sm += v[i].x + v[i].y + v[i].z + v[i].w;
      sq += v[i].x * v[i].x + v[i].y * v[i].y + v[i].z * v[i].z + v[i].w * v[i].w;
    }
#pragma unroll
    for (int m = 1; m < 32; m <<= 1) { sm += __shfl_xor(sm, m); sq += __shfl_xor(sq, m); }
    const float mu = sm * (1.f / 768.f);
    const float rs = rsqrtf(sq * (1.f / 768.f) - mu * mu + 1e-5f);
#pragma unroll
    for (int i = 0; i < 6; ++i) {
      const float4 w = *(const float4*)(nw1 + (l32 + 32 * i) * 4);
      const float4 b = *(const float4*)(nb1 + (l32 + 32 * i) * 4);
      v[i].x = (v[i].x - mu) * rs * w.x + b.x;
      v[i].y = (v[i].y - mu) * rs * w.y + b.y;
      v[i].z = (v[i].z - mu) * rs * w.z + b.z;
      v[i].w = (v[i].w - mu) * rs * w.w + b.w;
    }
    const float4 w2 = *(const float4*)(nw2 + l32 * 4);
    const float4 b2 = *(const float4*)(nb2 + l32 * 4);
#pragma unroll
    for (int i = 0; i < 6; ++i) {
      float s2 = v[i].x + v[i].y + v[i].z + v[i].w;
      float q2 = v[i].x * v[i].x + v[i].y * v[i].y + v[i].z * v[i].z + v[i].w * v[i].w;
#pragma unroll
      for (int m = 1; m < 32; m <<= 1) { s2 += __shfl_xor(s2, m); q2 += __shfl_xor(q2, m); }
      const float mu2 = s2 * (1.f / 128.f);
      const float rs2 = rsqrtf(q2 * (1.f / 128.f) - mu2 * mu2 + 1e-5f);
      const int row = s * 6 + i;
      uint2 o;
      o.x = pk2bf((v[i].x - mu2) * rs2 * w2.x + b2.x, (v[i].y - mu2) * rs2 * w2.y + b2.y);
      o.y = pk2bf((v[i].z - mu2) * rs2 * w2.z + b2.z, (v[i].w - mu2) * rs2 * w2.w + b2.w);
      *(uint2*)(XF + row * LDA + l32 * 4) = o;
    }
  }
  __syncthreads();

  // ---------- Q -> BA, K -> BB ----------
  {
    f32x4 acc[3][2] = {};
    gemm48T(XF, wt + 0, 128, acc, wave, lane16, kgrp);
    store48T(BA, acc, qb, wave, lane16, kgrp);
  }
  {
    f32x4 acc[3][2] = {};
    gemm48T(XF, wt + 16384, 128, acc, wave, lane16, kgrp);
    store48T(BB, acc, kb, wave, lane16, kgrp);
  }
  __syncthreads();

  // ---------- scores -> PS (bf16) ----------
  for (int si = tid; si < SLOTS * 72; si += 256) {
    const int slot = si / 72;
    const int rem  = si % 72;
    const int h    = rem / 36;
    const int qi   = (rem % 36) / 6;
    const int ki   = rem % 6;
    const u32* qr = (const u32*)(BA + (slot * 6 + qi) * LDA + h * 64);
    const u32* kr = (const u32*)(BB + (slot * 6 + ki) * LDA + h * 64);
    float a = 0.f;
#pragma unroll
    for (int j = 0; j < 32; j += 2) {
      const uint2 qa = *(const uint2*)(qr + j);
      const uint2 ka = *(const uint2*)(kr + j);
      const float2 q0 = bf2x2(qa.x), q1 = bf2x2(qa.y);
      const float2 k0 = bf2x2(ka.x), k1 = bf2x2(ka.y);
      a = fmaf(q0.x, k0.x, fmaf(q0.y, k0.y, fmaf(q1.x, k1.x, fmaf(q1.y, k1.y, a))));
    }
    PS[si] = f2bf(a * 0.125f);   // scale = 64^-0.5
  }
  __syncthreads();
  // ---------- softmax over ki (96 rows of 6) ----------
  if (tid < SLOTS * 12) {
    u16* pr = PS + tid * 6;
    float e[6];
    float m = bf2f(pr[0]);
#pragma unroll
    for (int k = 1; k < 6; ++k) m = fmaxf(m, bf2f(pr[k]));
    float ssum = 0.f;
#pragma unroll
    for (int k = 0; k < 6; ++k) { e[k] = EXP2F((bf2f(pr[k]) - m) * 1.44269504f); ssum += e[k]; }
    const float inv = __builtin_amdgcn_rcpf(ssum);
#pragma unroll
    for (int k = 0; k < 6; ++k) pr[k] = f2bf(e[k] * inv);
  }
  __syncthreads();

  // ---------- V -> BA (Q dead) ----------
  {
    f32x4 acc[3][2] = {};
    gemm48T(XF, wt + 32768, 128, acc, wave, lane16, kgrp);
    store48T(BA, acc, vb, wave, lane16, kgrp);
  }
  __syncthreads();

  // ---------- O = P @ V -> BB (K dead) ----------
  {
    const int d0 = (tid & 31) * 4;
    const int h  = d0 >> 6;
    const int r0 = tid >> 5;
#pragma unroll
    for (int p = 0; p < 6; ++p) {
      const int row  = r0 + 8 * p;
      const int slot = row / 6, qi = row % 6;
      const u16* pr = PS + (slot * 2 + h) * 36 + qi * 6;
      float o0 = 0, o1 = 0, o2 = 0, o3 = 0;
#pragma unroll
      for (int k = 0; k < 6; ++k) {
        const uint2 v2 = *(const uint2*)(BA + (slot * 6 + k) * LDA + d0);
        const float pw = bf2f(pr[k]);
        const float2 a = bf2x2(v2.x), b = bf2x2(v2.y);
        o0 = fmaf(pw, a.x, o0); o1 = fmaf(pw, a.y, o1);
        o2 = fmaf(pw, b.x, o2); o3 = fmaf(pw, b.y, o3);
      }
      uint2 o; o.x = pk2bf(o0, o1); o.y = pk2bf(o2, o3);
      *(uint2*)(BB + row * LDA + d0) = o;
    }
  }
  __syncthreads();

  // ---------- att_out = O @ ow + ob ; xf2 = xf + att_out -> XF ----------
  {
    f32x4 acc[3][2] = {};
    gemm48T(BB, wt + 49152, 128, acc, wave, lane16, kgrp);
#pragma unroll
    for (int c = 0; c < 2; ++c) {
      const int col0 = (wave + 4 * c) * 16 + kgrp * 4;
      const float4 bv = *(const float4*)(ob + col0);
#pragma unroll
      for (int xr = 0; xr < 3; ++xr) {
        u16* px = XF + (xr * 16 + lane16) * LDA + col0;
        const uint2 cur = *(const uint2*)px;
        const float2 lo = bf2x2(cur.x), hi = bf2x2(cur.y);
        uint2 o;
        o.x = pk2bf(lo.x + acc[xr][c][0] + bv.x, lo.y + acc[xr][c][1] + bv.y);
        o.y = pk2bf(hi.x + acc[xr][c][2] + bv.z, hi.y + acc[xr][c][3] + bv.w);
        *(uint2*)px = o;
      }
    }
  }
  __syncthreads();

  // ---------- H = LN2(xf2) -> BA (V dead) ----------
  {
    const int g = tid >> 5, l32 = tid & 31;
    const float4 w2 = *(const float4*)(nw2 + l32 * 4);
    const float4 b2 = *(const float4*)(nb2 + l32 * 4);
#pragma unroll
    for (int i = 0; i < 6; ++i) {
      const int row = g * 6 + i;
      const uint2 hv = *(const uint2*)(XF + row * LDA + l32 * 4);
      const float2 lo = bf2x2(hv.x), hi = bf2x2(hv.y);
      float s2 = lo.x + lo.y + hi.x + hi.y;
      float q2 = lo.x * lo.x + lo.y * lo.y + hi.x * hi.x + hi.y * hi.y;
#pragma unroll
      for (int m = 1; m < 32; m <<= 1) { s2 += __shfl_xor(s2, m); q2 += __shfl_xor(q2, m); }
      const float mu2 = s2 * (1.f / 128.f);
      const float rs2 = rsqrtf(q2 * (1.f / 128.f) - mu2 * mu2 + 1e-5f);
      uint2 o;
      o.x = pk2bf((lo.x - mu2) * rs2 * w2.x + b2.x, (lo.y - mu2) * rs2 * w2.y + b2.y);
      o.y = pk2bf((hi.x - mu2) * rs2 * w2.z + b2.z, (hi.y - mu2) * rs2 * w2.w + b2.w);
      *(uint2*)(BA + row * LDA + l32 * 4) = o;
    }
  }
  __syncthreads();

  // ---------- FF: acc2 = sum_t gelu(H @ ff1_t + b) @ ff2_t ----------
  // H fragments hoisted out of the t-loop (36 fewer ds_read_b128; 12 read-only VGPRs)
  bf16x8 hf[3][4];
#pragma unroll
  for (int xr = 0; xr < 3; ++xr)
#pragma unroll
    for (int ks = 0; ks < 4; ++ks)
      hf[xr][ks] = *(const bf16x8*)(BA + (xr * 16 + lane16) * LDA + ks * 32 + kgrp * 8);

  f32x4 acc2[3][2] = {};
#pragma unroll
  for (int t = 0; t < 4; ++t) {
    f32x4 g[3][2] = {};
    const u16* WT1 = wt + 65536 + t * 16384;
#pragma unroll
    for (int ks = 0; ks < 4; ++ks) {
      const int kk = ks * 32 + kgrp * 8;
      const bf16x8 b0 = *(const bf16x8*)(WT1 + ((wave)     * 16 + lane16) * 128 + kk);
      const bf16x8 b1 = *(const bf16x8*)(WT1 + ((wave + 4) * 16 + lane16) * 128 + kk);
      g[0][0] = MFMA32(b0, hf[0][ks], g[0][0]);
      g[1][0] = MFMA32(b0, hf[1][ks], g[1][0]);
      g[2][0] = MFMA32(b0, hf[2][ks], g[2][0]);
      g[0][1] = MFMA32(b1, hf[0][ks], g[0][1]);
      g[1][1] = MFMA32(b1, hf[1][ks], g[1][1]);
      g[2][1] = MFMA32(b1, hf[2][ks], g[2][1]);
    }
#pragma unroll
    for (int c = 0; c < 2; ++c) {
      const int col0 = (wave + 4 * c) * 16 + kgrp * 4;
      const float4 bv = *(const float4*)(f1b + t * 128 + col0);
#pragma unroll
      for (int xr = 0; xr < 3; ++xr) {
        uint2 o;
        o.x = pk2bf(gelu_f(g[xr][c][0] + bv.x), gelu_f(g[xr][c][1] + bv.y));
        o.y = pk2bf(gelu_f(g[xr][c][2] + bv.z), gelu_f(g[xr][c][3] + bv.w));
        *(uint2*)(BB + (xr * 16 + lane16) * LDA + col0) = o;
      }
    }
    __syncthreads();
    gemm48T(BB, wt + 131072 + t * 128, 512, acc2, wave, lane16, kgrp);
    __syncthreads();
  }

  // ---------- out = x + xf2 + ff_out + ff2b ----------
#pragma unroll
  for (int c = 0; c < 2; ++c) {
    const int col0 = (wave + 4 * c) * 16 + kgrp * 4;
    const float4 fb = *(const float4*)(f2b + col0);
#pragma unroll
    for (int xr = 0; xr < 3; ++xr) {
      const int row  = xr * 16 + lane16;
      const int slot = row / 6, ch = row % 6;
      const size_t gi = (size_t)(slot0 + slot) * 768 + ch * 128 + col0;
      const float4 xv = *(const float4*)(x + gi);
      const uint2 xf2v = *(const uint2*)(XF + row * LDA + col0);
      const float2 lo = bf2x2(xf2v.x), hi = bf2x2(xf2v.y);
      float4 o;
      o.x = xv.x + lo.x + acc2[xr][c][0] + fb.x;
      o.y = xv.y + lo.y + acc2[xr][c][1] + fb.y;
      o.z = xv.z + hi.x + acc2[xr][c][2] + fb.z;
      o.w = xv.w + hi.y + acc2[xr][c][3] + fb.w;
      *(float4*)(out + gi) = o;
    }
  }
}

extern "C" void kernel_launch(void* const* d_in, const int* in_sizes, int n_in,
                              void* d_out, int out_size, void* d_ws, size_t ws_size,
                              hipStream_t stream) {
  const float* x   = (const float*)d_in[0];
  const float* nw1 = (const float*)d_in[1];
  const float* nb1 = (const float*)d_in[2];
  const float* nw2 = (const float*)d_in[3];
  const float* nb2 = (const float*)d_in[4];
  const float* qw  = (const float*)d_in[5];
  const float* qb  = (const float*)d_in[6];
  const float* kw  = (const float*)d_in[7];
  const float* kb  = (const float*)d_in[8];
  const float* vw  = (const float*)d_in[9];
  const float* vb  = (const float*)d_in[10];
  const float* ow  = (const float*)d_in[11];
  const float* ob  = (const float*)d_in[12];
  const float* f1w = (const float*)d_in[13];
  const float* f1b = (const float*)d_in[14];
  const float* f2w = (const float*)d_in[15];
  const float* f2b = (const float*)d_in[16];
  u16* wt = (u16*)d_ws;   // 196608 u16 = 384 KB

  convert_w<<<768, 256, 0, stream>>>(qw, kw, vw, ow, f1w, f2w, wt);

  const int M = in_sizes[0] / 768;   // 32768 slots
  mitra_main<<<M / SLOTS, 256, 0, stream>>>(x, nw1, nb1, nw2, nb2,
                                            qb, kb, vb, ob, f1b, f2b,
                                            wt, (float*)d_out);
}

// Round 6
// 226.290 us; speedup vs baseline: 1.1537x; 1.1537x over previous
//
#include <hip/hip_runtime.h>
#include <hip/hip_bf16.h>

typedef unsigned short u16;
typedef unsigned int u32;
using bf16x8 = __attribute__((ext_vector_type(8))) short;
using f32x4  = __attribute__((ext_vector_type(4))) float;

#define LDA   136   // 128 + 8 pad (16B-aligned rows, 2-lanes/bank = free)
#define SLOTS 8
#define NROWS 48    // SLOTS * 6

__device__ __forceinline__ u32 pk2bf(float a, float b) {
  u32 r;
  asm("v_cvt_pk_bf16_f32 %0, %1, %2" : "=v"(r) : "v"(a), "v"(b));
  return r;
}
__device__ __forceinline__ u16 f2bf(float f) { return (u16)pk2bf(f, f); }
__device__ __forceinline__ float bf2f(u16 h) {
  union { u32 u; float f; } v; v.u = ((u32)h) << 16;
  return v.f;
}
__device__ __forceinline__ float2 bf2x2(u32 u) {
  union { u32 u; float f; } a, b; a.u = u << 16; b.u = u & 0xffff0000u;
  return make_float2(a.f, b.f);
}

#if __has_builtin(__builtin_amdgcn_exp2f)
#define EXP2F(x) __builtin_amdgcn_exp2f(x)
#else
#define EXP2F(x) exp2f(x)
#endif

#define MFMA32(a, b, c) __builtin_amdgcn_mfma_f32_16x16x32_bf16(a, b, c, 0, 0, 0)

// tanh-form GELU: x*sigmoid(x*(1.5957691 + 0.0713548*x^2)); |err vs exact erf| < 4e-4
// (numerics validated R3/R4/R5: absmax stayed 0.0625)
__device__ __forceinline__ float gelu_f(float x) {
  const float a = x * x;
  const float b = fmaf(-0.10294538f, a, -2.3022077f);
  const float e = EXP2F(x * b);
  return x * __builtin_amdgcn_rcpf(1.f + e);
}

// ---------------- weight convert + transpose to bf16 ----------------
// ws layout (u16): qwT[128*128] kwT vwT owT | ff1T[512*128] | ff2T[128*512]
__global__ void convert_w(const float* __restrict__ qw, const float* __restrict__ kw,
                          const float* __restrict__ vw, const float* __restrict__ ow,
                          const float* __restrict__ f1, const float* __restrict__ f2,
                          u16* __restrict__ o) {
  int i = blockIdx.x * 256 + threadIdx.x;
  if (i < 65536) {
    int which = i >> 14;
    const float* W = which == 0 ? qw : which == 1 ? kw : which == 2 ? vw : ow;
    int t = i & 16383;
    int n = t >> 7, k = t & 127;
    o[i] = f2bf(W[k * 128 + n]);
  } else if (i < 131072) {
    int t = i - 65536;
    int n = t >> 7, k = t & 127;
    o[i] = f2bf(f1[k * 512 + n]);
  } else if (i < 196608) {
    int t = i - 131072;
    int n = t >> 9, k = t & 511;
    o[i] = f2bf(f2[k * 128 + n]);
  }
}

// mfma(F1,F2): lane(l16,kg) holds D[f2row=l16][f1row=kg*4+r]
// gemm48T: Y = A(48x128) @ W; WT rows as F1 -> lane holds Y[xrow=l16][4 consecutive wcols]
__device__ __forceinline__ void gemm48T(const u16* __restrict__ A, const u16* __restrict__ WT,
                                        int ldw, f32x4 acc[3][2],
                                        int wave, int lane16, int kgrp) {
#pragma unroll
  for (int ks = 0; ks < 4; ++ks) {
    const int kk = ks * 32 + kgrp * 8;
    bf16x8 a0 = *(const bf16x8*)(A + (0 * 16 + lane16) * LDA + kk);
    bf16x8 a1 = *(const bf16x8*)(A + (1 * 16 + lane16) * LDA + kk);
    bf16x8 a2 = *(const bf16x8*)(A + (2 * 16 + lane16) * LDA + kk);
    bf16x8 b0 = *(const bf16x8*)(WT + ((wave)     * 16 + lane16) * ldw + kk);
    bf16x8 b1 = *(const bf16x8*)(WT + ((wave + 4) * 16 + lane16) * ldw + kk);
    __builtin_amdgcn_s_setprio(1);
    acc[0][0] = MFMA32(b0, a0, acc[0][0]);
    acc[1][0] = MFMA32(b0, a1, acc[1][0]);
    acc[2][0] = MFMA32(b0, a2, acc[2][0]);
    acc[0][1] = MFMA32(b1, a0, acc[0][1]);
    acc[1][1] = MFMA32(b1, a1, acc[1][1]);
    acc[2][1] = MFMA32(b1, a2, acc[2][1]);
    __builtin_amdgcn_s_setprio(0);
  }
}

__device__ __forceinline__ void store48T(u16* __restrict__ dst, f32x4 acc[3][2],
                                         const float* __restrict__ bias,
                                         int wave, int lane16, int kgrp) {
#pragma unroll
  for (int c = 0; c < 2; ++c) {
    const int col0 = (wave + 4 * c) * 16 + kgrp * 4;
    const float4 bv = *(const float4*)(bias + col0);
#pragma unroll
    for (int xr = 0; xr < 3; ++xr) {
      uint2 o;
      o.x = pk2bf(acc[xr][c][0] + bv.x, acc[xr][c][1] + bv.y);
      o.y = pk2bf(acc[xr][c][2] + bv.z, acc[xr][c][3] + bv.w);
      *(uint2*)(dst + (xr * 16 + lane16) * LDA + col0) = o;
    }
  }
}

__global__ __launch_bounds__(256, 4) void mitra_main(
    const float* __restrict__ x,
    const float* __restrict__ nw1, const float* __restrict__ nb1,
    const float* __restrict__ nw2, const float* __restrict__ nb2,
    const float* __restrict__ qb,  const float* __restrict__ kb,
    const float* __restrict__ vb,  const float* __restrict__ ob,
    const float* __restrict__ f1b, const float* __restrict__ f2b,
    const u16* __restrict__ wt, float* __restrict__ out) {
  __shared__ u16 XF[NROWS * LDA];   // xf -> xf2
  __shared__ u16 BA[NROWS * LDA];   // Q -> V -> H
  __shared__ u16 BB[NROWS * LDA];   // K -> O -> G
  __shared__ u16 PS[SLOTS * 2 * 36];   // softmax probs, bf16

  const int tid    = threadIdx.x;
  const int wave   = tid >> 6;
  const int lane   = tid & 63;
  const int lane16 = lane & 15;
  const int kgrp   = lane >> 4;
  const long slot0 = (long)blockIdx.x * SLOTS;

  // ---------- Phase 0: LN1(768) + LN2(128) -> XF ----------
  {
    const int s = tid >> 5, l32 = tid & 31;
    const float* xr = x + (size_t)(slot0 + s) * 768;
    float4 v[6];
    float sm = 0.f, sq = 0.f;
#pragma unroll
    for (int i = 0; i < 6; ++i) {
      v[i] = *(const float4*)(xr + (l32 + 32 * i) * 4);
      sm += v[i].x + v[i].y + v[i].z + v[i].w;
      sq += v[i].x * v[i].x + v[i].y * v[i].y + v[i].z * v[i].z + v[i].w * v[i].w;
    }
#pragma unroll
    for (int m = 1; m < 32; m <<= 1) { sm += __shfl_xor(sm, m); sq += __shfl_xor(sq, m); }
    const float mu = sm * (1.f / 768.f);
    const float rs = rsqrtf(sq * (1.f / 768.f) - mu * mu + 1e-5f);
#pragma unroll
    for (int i = 0; i < 6; ++i) {
      const float4 w = *(const float4*)(nw1 + (l32 + 32 * i) * 4);
      const float4 b = *(const float4*)(nb1 + (l32 + 32 * i) * 4);
      v[i].x = (v[i].x - mu) * rs * w.x + b.x;
      v[i].y = (v[i].y - mu) * rs * w.y + b.y;
      v[i].z = (v[i].z - mu) * rs * w.z + b.z;
      v[i].w = (v[i].w - mu) * rs * w.w + b.w;
    }
    const float4 w2 = *(const float4*)(nw2 + l32 * 4);
    const float4 b2 = *(const float4*)(nb2 + l32 * 4);
#pragma unroll
    for (int i = 0; i < 6; ++i) {
      float s2 = v[i].x + v[i].y + v[i].z + v[i].w;
      float q2 = v[i].x * v[i].x + v[i].y * v[i].y + v[i].z * v[i].z + v[i].w * v[i].w;
#pragma unroll
      for (int m = 1; m < 32; m <<= 1) { s2 += __shfl_xor(s2, m); q2 += __shfl_xor(q2, m); }
      const float mu2 = s2 * (1.f / 128.f);
      const float rs2 = rsqrtf(q2 * (1.f / 128.f) - mu2 * mu2 + 1e-5f);
      const int row = s * 6 + i;
      uint2 o;
      o.x = pk2bf((v[i].x - mu2) * rs2 * w2.x + b2.x, (v[i].y - mu2) * rs2 * w2.y + b2.y);
      o.y = pk2bf((v[i].z - mu2) * rs2 * w2.z + b2.z, (v[i].w - mu2) * rs2 * w2.w + b2.w);
      *(uint2*)(XF + row * LDA + l32 * 4) = o;
    }
  }
  __syncthreads();

  // ---------- Q -> BA, K -> BB ----------
  {
    f32x4 acc[3][2] = {};
    gemm48T(XF, wt + 0, 128, acc, wave, lane16, kgrp);
    store48T(BA, acc, qb, wave, lane16, kgrp);
  }
  {
    f32x4 acc[3][2] = {};
    gemm48T(XF, wt + 16384, 128, acc, wave, lane16, kgrp);
    store48T(BB, acc, kb, wave, lane16, kgrp);
  }
  __syncthreads();

  // ---------- scores -> PS (bf16) ----------
  for (int si = tid; si < SLOTS * 72; si += 256) {
    const int slot = si / 72;
    const int rem  = si % 72;
    const int h    = rem / 36;
    const int qi   = (rem % 36) / 6;
    const int ki   = rem % 6;
    const u32* qr = (const u32*)(BA + (slot * 6 + qi) * LDA + h * 64);
    const u32* kr = (const u32*)(BB + (slot * 6 + ki) * LDA + h * 64);
    float a = 0.f;
#pragma unroll
    for (int j = 0; j < 32; j += 2) {
      const uint2 qa = *(const uint2*)(qr + j);
      const uint2 ka = *(const uint2*)(kr + j);
      const float2 q0 = bf2x2(qa.x), q1 = bf2x2(qa.y);
      const float2 k0 = bf2x2(ka.x), k1 = bf2x2(ka.y);
      a = fmaf(q0.x, k0.x, fmaf(q0.y, k0.y, fmaf(q1.x, k1.x, fmaf(q1.y, k1.y, a))));
    }
    PS[si] = f2bf(a * 0.125f);   // scale = 64^-0.5
  }
  __syncthreads();

  // ---------- V -> BA (Q dead) with softmax merged into the same phase ----------
  // V-GEMM reads XF, writes BA; softmax reads/writes PS only -> no hazard, one barrier saved.
  {
    f32x4 acc[3][2] = {};
    gemm48T(XF, wt + 32768, 128, acc, wave, lane16, kgrp);
    store48T(BA, acc, vb, wave, lane16, kgrp);
  }
  if (tid < SLOTS * 12) {
    u16* pr = PS + tid * 6;
    float e[6];
    float m = bf2f(pr[0]);
#pragma unroll
    for (int k = 1; k < 6; ++k) m = fmaxf(m, bf2f(pr[k]));
    float ssum = 0.f;
#pragma unroll
    for (int k = 0; k < 6; ++k) { e[k] = EXP2F((bf2f(pr[k]) - m) * 1.44269504f); ssum += e[k]; }
    const float inv = __builtin_amdgcn_rcpf(ssum);
#pragma unroll
    for (int k = 0; k < 6; ++k) pr[k] = f2bf(e[k] * inv);
  }
  __syncthreads();

  // ---------- O = P @ V -> BB (K dead) ----------
  {
    const int d0 = (tid & 31) * 4;
    const int h  = d0 >> 6;
    const int r0 = tid >> 5;
#pragma unroll
    for (int p = 0; p < 6; ++p) {
      const int row  = r0 + 8 * p;
      const int slot = row / 6, qi = row % 6;
      const u16* pr = PS + (slot * 2 + h) * 36 + qi * 6;
      float o0 = 0, o1 = 0, o2 = 0, o3 = 0;
#pragma unroll
      for (int k = 0; k < 6; ++k) {
        const uint2 v2 = *(const uint2*)(BA + (slot * 6 + k) * LDA + d0);
        const float pw = bf2f(pr[k]);
        const float2 a = bf2x2(v2.x), b = bf2x2(v2.y);
        o0 = fmaf(pw, a.x, o0); o1 = fmaf(pw, a.y, o1);
        o2 = fmaf(pw, b.x, o2); o3 = fmaf(pw, b.y, o3);
      }
      uint2 o; o.x = pk2bf(o0, o1); o.y = pk2bf(o2, o3);
      *(uint2*)(BB + row * LDA + d0) = o;
    }
  }
  __syncthreads();

  // ---------- att_out = O @ ow + ob ; xf2 = xf + att_out -> XF ----------
  {
    f32x4 acc[3][2] = {};
    gemm48T(BB, wt + 49152, 128, acc, wave, lane16, kgrp);
#pragma unroll
    for (int c = 0; c < 2; ++c) {
      const int col0 = (wave + 4 * c) * 16 + kgrp * 4;
      const float4 bv = *(const float4*)(ob + col0);
#pragma unroll
      for (int xr = 0; xr < 3; ++xr) {
        u16* px = XF + (xr * 16 + lane16) * LDA + col0;
        const uint2 cur = *(const uint2*)px;
        const float2 lo = bf2x2(cur.x), hi = bf2x2(cur.y);
        uint2 o;
        o.x = pk2bf(lo.x + acc[xr][c][0] + bv.x, lo.y + acc[xr][c][1] + bv.y);
        o.y = pk2bf(hi.x + acc[xr][c][2] + bv.z, hi.y + acc[xr][c][3] + bv.w);
        *(uint2*)px = o;
      }
    }
  }
  __syncthreads();

  // ---------- H = LN2(xf2) -> BA (V dead) ----------
  {
    const int g = tid >> 5, l32 = tid & 31;
    const float4 w2 = *(const float4*)(nw2 + l32 * 4);
    const float4 b2 = *(const float4*)(nb2 + l32 * 4);
#pragma unroll
    for (int i = 0; i < 6; ++i) {
      const int row = g * 6 + i;
      const uint2 hv = *(const uint2*)(XF + row * LDA + l32 * 4);
      const float2 lo = bf2x2(hv.x), hi = bf2x2(hv.y);
      float s2 = lo.x + lo.y + hi.x + hi.y;
      float q2 = lo.x * lo.x + lo.y * lo.y + hi.x * hi.x + hi.y * hi.y;
#pragma unroll
      for (int m = 1; m < 32; m <<= 1) { s2 += __shfl_xor(s2, m); q2 += __shfl_xor(q2, m); }
      const float mu2 = s2 * (1.f / 128.f);
      const float rs2 = rsqrtf(q2 * (1.f / 128.f) - mu2 * mu2 + 1e-5f);
      uint2 o;
      o.x = pk2bf((lo.x - mu2) * rs2 * w2.x + b2.x, (lo.y - mu2) * rs2 * w2.y + b2.y);
      o.y = pk2bf((hi.x - mu2) * rs2 * w2.z + b2.z, (hi.y - mu2) * rs2 * w2.w + b2.w);
      *(uint2*)(BA + row * LDA + l32 * 4) = o;
    }
  }
  __syncthreads();

  // ---------- FF: acc2 = sum_t gelu(H @ ff1_t + b) @ ff2_t ----------
  // (no register hoists across barriers: R4/R5 spill lesson)
  f32x4 acc2[3][2] = {};
#pragma unroll
  for (int t = 0; t < 4; ++t) {
    f32x4 g[3][2] = {};
    gemm48T(BA, wt + 65536 + t * 16384, 128, g, wave, lane16, kgrp);
#pragma unroll
    for (int c = 0; c < 2; ++c) {
      const int col0 = (wave + 4 * c) * 16 + kgrp * 4;
      const float4 bv = *(const float4*)(f1b + t * 128 + col0);
#pragma unroll
      for (int xr = 0; xr < 3; ++xr) {
        uint2 o;
        o.x = pk2bf(gelu_f(g[xr][c][0] + bv.x), gelu_f(g[xr][c][1] + bv.y));
        o.y = pk2bf(gelu_f(g[xr][c][2] + bv.z), gelu_f(g[xr][c][3] + bv.w));
        *(uint2*)(BB + (xr * 16 + lane16) * LDA + col0) = o;
      }
    }
    __syncthreads();
    gemm48T(BB, wt + 131072 + t * 128, 512, acc2, wave, lane16, kgrp);
    __syncthreads();
  }

  // ---------- out = x + xf2 + ff_out + ff2b ----------
#pragma unroll
  for (int c = 0; c < 2; ++c) {
    const int col0 = (wave + 4 * c) * 16 + kgrp * 4;
    const float4 fb = *(const float4*)(f2b + col0);
#pragma unroll
    for (int xr = 0; xr < 3; ++xr) {
      const int row  = xr * 16 + lane16;
      const int slot = row / 6, ch = row % 6;
      const size_t gi = (size_t)(slot0 + slot) * 768 + ch * 128 + col0;
      const float4 xv = *(const float4*)(x + gi);
      const uint2 xf2v = *(const uint2*)(XF + row * LDA + col0);
      const float2 lo = bf2x2(xf2v.x), hi = bf2x2(xf2v.y);
      float4 o;
      o.x = xv.x + lo.x + acc2[xr][c][0] + fb.x;
      o.y = xv.y + lo.y + acc2[xr][c][1] + fb.y;
      o.z = xv.z + hi.x + acc2[xr][c][2] + fb.z;
      o.w = xv.w + hi.y + acc2[xr][c][3] + fb.w;
      *(float4*)(out + gi) = o;
    }
  }
}

extern "C" void kernel_launch(void* const* d_in, const int* in_sizes, int n_in,
                              void* d_out, int out_size, void* d_ws, size_t ws_size,
                              hipStream_t stream) {
  const float* x   = (const float*)d_in[0];
  const float* nw1 = (const float*)d_in[1];
  const float* nb1 = (const float*)d_in[2];
  const float* nw2 = (const float*)d_in[3];
  const float* nb2 = (const float*)d_in[4];
  const float* qw  = (const float*)d_in[5];
  const float* qb  = (const float*)d_in[6];
  const float* kw  = (const float*)d_in[7];
  const float* kb  = (const float*)d_in[8];
  const float* vw  = (const float*)d_in[9];
  const float* vb  = (const float*)d_in[10];
  const float* ow  = (const float*)d_in[11];
  const float* ob  = (const float*)d_in[12];
  const float* f1w = (const float*)d_in[13];
  const float* f1b = (const float*)d_in[14];
  const float* f2w = (const float*)d_in[15];
  const float* f2b = (const float*)d_in[16];
  u16* wt = (u16*)d_ws;   // 196608 u16 = 384 KB

  convert_w<<<768, 256, 0, stream>>>(qw, kw, vw, ow, f1w, f2w, wt);

  const int M = in_sizes[0] / 768;   // 32768 slots
  mitra_main<<<M / SLOTS, 256, 0, stream>>>(x, nw1, nb1, nw2, nb2,
                                            qb, kb, vb, ob, f1b, f2b,
                                            wt, (float*)d_out);
}

// Round 8
// 224.891 us; speedup vs baseline: 1.1609x; 1.0062x over previous
//
#include <hip/hip_runtime.h>
#include <hip/hip_bf16.h>

typedef unsigned short u16;
typedef unsigned int u32;
using bf16x8 = __attribute__((ext_vector_type(8))) short;
using f32x4  = __attribute__((ext_vector_type(4))) float;

#define LDA   136   // 128 + 8 pad (16B-aligned rows, near-free bank aliasing)
#define SLOTS 8
#define NROWS 48    // SLOTS * 6

__device__ __forceinline__ u32 pk2bf(float a, float b) {
  u32 r;
  asm("v_cvt_pk_bf16_f32 %0, %1, %2" : "=v"(r) : "v"(a), "v"(b));
  return r;
}
__device__ __forceinline__ u16 f2bf(float f) { return (u16)pk2bf(f, f); }
__device__ __forceinline__ float bf2f(u16 h) {
  union { u32 u; float f; } v; v.u = ((u32)h) << 16;
  return v.f;
}
__device__ __forceinline__ float2 bf2x2(u32 u) {
  union { u32 u; float f; } a, b; a.u = u << 16; b.u = u & 0xffff0000u;
  return make_float2(a.f, b.f);
}

#if __has_builtin(__builtin_amdgcn_exp2f)
#define EXP2F(x) __builtin_amdgcn_exp2f(x)
#else
#define EXP2F(x) exp2f(x)
#endif

#define MFMA32(a, b, c) __builtin_amdgcn_mfma_f32_16x16x32_bf16(a, b, c, 0, 0, 0)

// tanh-form GELU (validated R3-R6: absmax stays 0.0625)
__device__ __forceinline__ float gelu_f(float x) {
  const float a = x * x;
  const float b = fmaf(-0.10294538f, a, -2.3022077f);
  const float e = EXP2F(x * b);
  return x * __builtin_amdgcn_rcpf(1.f + e);
}

// ---------------- weight convert + transpose to bf16 ----------------
// ws layout (u16): qwT[128*128] kwT vwT owT | ff1T[512*128] | ff2T[128*512]
__global__ void convert_w(const float* __restrict__ qw, const float* __restrict__ kw,
                          const float* __restrict__ vw, const float* __restrict__ ow,
                          const float* __restrict__ f1, const float* __restrict__ f2,
                          u16* __restrict__ o) {
  int i = blockIdx.x * 256 + threadIdx.x;
  if (i < 65536) {
    int which = i >> 14;
    const float* W = which == 0 ? qw : which == 1 ? kw : which == 2 ? vw : ow;
    int t = i & 16383;
    int n = t >> 7, k = t & 127;
    o[i] = f2bf(W[k * 128 + n]);
  } else if (i < 131072) {
    int t = i - 65536;
    int n = t >> 7, k = t & 127;
    o[i] = f2bf(f1[k * 512 + n]);
  } else if (i < 196608) {
    int t = i - 131072;
    int n = t >> 9, k = t & 511;
    o[i] = f2bf(f2[k * 128 + n]);
  }
}

// mfma(F1,F2): lane(l16,kg) holds D[f2row=l16][f1row=kg*4+r]
// gemm48T: Y = A(48x128) @ W; WT rows as F1 -> lane holds Y[xrow=l16][4 consecutive wcols]
__device__ __forceinline__ void gemm48T(const u16* __restrict__ A, const u16* __restrict__ WT,
                                        int ldw, f32x4 acc[3][2],
                                        int wave, int lane16, int kgrp) {
#pragma unroll
  for (int ks = 0; ks < 4; ++ks) {
    const int kk = ks * 32 + kgrp * 8;
    bf16x8 a0 = *(const bf16x8*)(A + (0 * 16 + lane16) * LDA + kk);
    bf16x8 a1 = *(const bf16x8*)(A + (1 * 16 + lane16) * LDA + kk);
    bf16x8 a2 = *(const bf16x8*)(A + (2 * 16 + lane16) * LDA + kk);
    bf16x8 b0 = *(const bf16x8*)(WT + ((wave)     * 16 + lane16) * ldw + kk);
    bf16x8 b1 = *(const bf16x8*)(WT + ((wave + 4) * 16 + lane16) * ldw + kk);
    __builtin_amdgcn_s_setprio(1);
    acc[0][0] = MFMA32(b0, a0, acc[0][0]);
    acc[1][0] = MFMA32(b0, a1, acc[1][0]);
    acc[2][0] = MFMA32(b0, a2, acc[2][0]);
    acc[0][1] = MFMA32(b1, a0, acc[0][1]);
    acc[1][1] = MFMA32(b1, a1, acc[1][1]);
    acc[2][1] = MFMA32(b1, a2, acc[2][1]);
    __builtin_amdgcn_s_setprio(0);
  }
}

__device__ __forceinline__ void store48T(u16* __restrict__ dst, f32x4 acc[3][2],
                                         const float* __restrict__ bias,
                                         int wave, int lane16, int kgrp) {
#pragma unroll
  for (int c = 0; c < 2; ++c) {
    const int col0 = (wave + 4 * c) * 16 + kgrp * 4;
    const float4 bv = *(const float4*)(bias + col0);
#pragma unroll
    for (int xr = 0; xr < 3; ++xr) {
      uint2 o;
      o.x = pk2bf(acc[xr][c][0] + bv.x, acc[xr][c][1] + bv.y);
      o.y = pk2bf(acc[xr][c][2] + bv.z, acc[xr][c][3] + bv.w);
      *(uint2*)(dst + (xr * 16 + lane16) * LDA + col0) = o;
    }
  }
}

__global__ __launch_bounds__(256, 4) void mitra_main(
    const float* __restrict__ x,
    const float* __restrict__ nw1, const float* __restrict__ nb1,
    const float* __restrict__ nw2, const float* __restrict__ nb2,
    const float* __restrict__ qb,  const float* __restrict__ kb,
    const float* __restrict__ vb,  const float* __restrict__ ob,
    const float* __restrict__ f1b, const float* __restrict__ f2b,
    const u16* __restrict__ wt, float* __restrict__ out) {
  __shared__ u16 XF[NROWS * LDA];   // xf -> xf2 -> FF G ping buffer
  __shared__ u16 BA[NROWS * LDA];   // Q -> V -> H
  __shared__ u16 BB[NROWS * LDA];   // K -> O -> FF G pong buffer
  __shared__ u16 PS[SLOTS * 2 * 36];   // softmax probs, bf16

  const int tid    = threadIdx.x;
  const int wave   = tid >> 6;
  const int lane   = tid & 63;
  const int lane16 = lane & 15;
  const int kgrp   = lane >> 4;
  const long slot0 = (long)blockIdx.x * SLOTS;

  // ---------- Phase 0: LN1(768) + LN2(128) -> XF ----------
  {
    const int s = tid >> 5, l32 = tid & 31;
    const float* xr = x + (size_t)(slot0 + s) * 768;
    float4 v[6];
    float sm = 0.f, sq = 0.f;
#pragma unroll
    for (int i = 0; i < 6; ++i) {
      v[i] = *(const float4*)(xr + (l32 + 32 * i) * 4);
      sm += v[i].x + v[i].y + v[i].z + v[i].w;
      sq += v[i].x * v[i].x + v[i].y * v[i].y + v[i].z * v[i].z + v[i].w * v[i].w;
    }
#pragma unroll
    for (int m = 1; m < 32; m <<= 1) { sm += __shfl_xor(sm, m); sq += __shfl_xor(sq, m); }
    const float mu = sm * (1.f / 768.f);
    const float rs = rsqrtf(sq * (1.f / 768.f) - mu * mu + 1e-5f);
#pragma unroll
    for (int i = 0; i < 6; ++i) {
      const float4 w = *(const float4*)(nw1 + (l32 + 32 * i) * 4);
      const float4 b = *(const float4*)(nb1 + (l32 + 32 * i) * 4);
      v[i].x = (v[i].x - mu) * rs * w.x + b.x;
      v[i].y = (v[i].y - mu) * rs * w.y + b.y;
      v[i].z = (v[i].z - mu) * rs * w.z + b.z;
      v[i].w = (v[i].w - mu) * rs * w.w + b.w;
    }
    const float4 w2 = *(const float4*)(nw2 + l32 * 4);
    const float4 b2 = *(const float4*)(nb2 + l32 * 4);
#pragma unroll
    for (int i = 0; i < 6; ++i) {
      float s2 = v[i].x + v[i].y + v[i].z + v[i].w;
      float q2 = v[i].x * v[i].x + v[i].y * v[i].y + v[i].z * v[i].z + v[i].w * v[i].w;
#pragma unroll
      for (int m = 1; m < 32; m <<= 1) { s2 += __shfl_xor(s2, m); q2 += __shfl_xor(q2, m); }
      const float mu2 = s2 * (1.f / 128.f);
      const float rs2 = rsqrtf(q2 * (1.f / 128.f) - mu2 * mu2 + 1e-5f);
      const int row = s * 6 + i;
      uint2 o;
      o.x = pk2bf((v[i].x - mu2) * rs2 * w2.x + b2.x, (v[i].y - mu2) * rs2 * w2.y + b2.y);
      o.y = pk2bf((v[i].z - mu2) * rs2 * w2.z + b2.z, (v[i].w - mu2) * rs2 * w2.w + b2.w);
      *(uint2*)(XF + row * LDA + l32 * 4) = o;
    }
  }
  __syncthreads();

  // ---------- Q -> BA, K -> BB ----------
  {
    f32x4 acc[3][2] = {};
    gemm48T(XF, wt + 0, 128, acc, wave, lane16, kgrp);
    store48T(BA, acc, qb, wave, lane16, kgrp);
  }
  {
    f32x4 acc[3][2] = {};
    gemm48T(XF, wt + 16384, 128, acc, wave, lane16, kgrp);
    store48T(BB, acc, kb, wave, lane16, kgrp);
  }
  __syncthreads();

  // ---------- scores -> PS (bf16) ----------
  for (int si = tid; si < SLOTS * 72; si += 256) {
    const int slot = si / 72;
    const int rem  = si % 72;
    const int h    = rem / 36;
    const int qi   = (rem % 36) / 6;
    const int ki   = rem % 6;
    const u32* qr = (const u32*)(BA + (slot * 6 + qi) * LDA + h * 64);
    const u32* kr = (const u32*)(BB + (slot * 6 + ki) * LDA + h * 64);
    float a = 0.f;
#pragma unroll
    for (int j = 0; j < 32; j += 2) {
      const uint2 qa = *(const uint2*)(qr + j);
      const uint2 ka = *(const uint2*)(kr + j);
      const float2 q0 = bf2x2(qa.x), q1 = bf2x2(qa.y);
      const float2 k0 = bf2x2(ka.x), k1 = bf2x2(ka.y);
      a = fmaf(q0.x, k0.x, fmaf(q0.y, k0.y, fmaf(q1.x, k1.x, fmaf(q1.y, k1.y, a))));
    }
    PS[si] = f2bf(a * 0.125f);   // scale = 64^-0.5
  }
  __syncthreads();

  // ---------- V -> BA (Q dead) with softmax merged into the same phase ----------
  {
    f32x4 acc[3][2] = {};
    gemm48T(XF, wt + 32768, 128, acc, wave, lane16, kgrp);
    store48T(BA, acc, vb, wave, lane16, kgrp);
  }
  if (tid < SLOTS * 12) {
    u16* pr = PS + tid * 6;
    float e[6];
    float m = bf2f(pr[0]);
#pragma unroll
    for (int k = 1; k < 6; ++k) m = fmaxf(m, bf2f(pr[k]));
    float ssum = 0.f;
#pragma unroll
    for (int k = 0; k < 6; ++k) { e[k] = EXP2F((bf2f(pr[k]) - m) * 1.44269504f); ssum += e[k]; }
    const float inv = __builtin_amdgcn_rcpf(ssum);
#pragma unroll
    for (int k = 0; k < 6; ++k) pr[k] = f2bf(e[k] * inv);
  }
  __syncthreads();

  // ---------- O = P @ V -> BB (K dead) ----------
  {
    const int d0 = (tid & 31) * 4;
    const int h  = d0 >> 6;
    const int r0 = tid >> 5;
#pragma unroll
    for (int p = 0; p < 6; ++p) {
      const int row  = r0 + 8 * p;
      const int slot = row / 6, qi = row % 6;
      const u16* pr = PS + (slot * 2 + h) * 36 + qi * 6;
      float o0 = 0, o1 = 0, o2 = 0, o3 = 0;
#pragma unroll
      for (int k = 0; k < 6; ++k) {
        const uint2 v2 = *(const uint2*)(BA + (slot * 6 + k) * LDA + d0);
        const float pw = bf2f(pr[k]);
        const float2 a = bf2x2(v2.x), b = bf2x2(v2.y);
        o0 = fmaf(pw, a.x, o0); o1 = fmaf(pw, a.y, o1);
        o2 = fmaf(pw, b.x, o2); o3 = fmaf(pw, b.y, o3);
      }
      uint2 o; o.x = pk2bf(o0, o1); o.y = pk2bf(o2, o3);
      *(uint2*)(BB + row * LDA + d0) = o;
    }
  }
  __syncthreads();

  // ---------- att_out = O @ ow + ob ; xf2 = xf + att_out -> XF ----------
  {
    f32x4 acc[3][2] = {};
    gemm48T(BB, wt + 49152, 128, acc, wave, lane16, kgrp);
#pragma unroll
    for (int c = 0; c < 2; ++c) {
      const int col0 = (wave + 4 * c) * 16 + kgrp * 4;
      const float4 bv = *(const float4*)(ob + col0);
#pragma unroll
      for (int xr = 0; xr < 3; ++xr) {
        u16* px = XF + (xr * 16 + lane16) * LDA + col0;
        const uint2 cur = *(const uint2*)px;
        const float2 lo = bf2x2(cur.x), hi = bf2x2(cur.y);
        uint2 o;
        o.x = pk2bf(lo.x + acc[xr][c][0] + bv.x, lo.y + acc[xr][c][1] + bv.y);
        o.y = pk2bf(hi.x + acc[xr][c][2] + bv.z, hi.y + acc[xr][c][3] + bv.w);
        *(uint2*)px = o;
      }
    }
  }
  __syncthreads();

  // ---------- H = LN2(xf2) -> BA (V dead) ----------
  {
    const int g = tid >> 5, l32 = tid & 31;
    const float4 w2 = *(const float4*)(nw2 + l32 * 4);
    const float4 b2 = *(const float4*)(nb2 + l32 * 4);
#pragma unroll
    for (int i = 0; i < 6; ++i) {
      const int row = g * 6 + i;
      const uint2 hv = *(const uint2*)(XF + row * LDA + l32 * 4);
      const float2 lo = bf2x2(hv.x), hi = bf2x2(hv.y);
      float s2 = lo.x + lo.y + hi.x + hi.y;
      float q2 = lo.x * lo.x + lo.y * lo.y + hi.x * hi.x + hi.y * hi.y;
#pragma unroll
      for (int m = 1; m < 32; m <<= 1) { s2 += __shfl_xor(s2, m); q2 += __shfl_xor(q2, m); }
      const float mu2 = s2 * (1.f / 128.f);
      const float rs2 = rsqrtf(q2 * (1.f / 128.f) - mu2 * mu2 + 1e-5f);
      uint2 o;
      o.x = pk2bf((lo.x - mu2) * rs2 * w2.x + b2.x, (lo.y - mu2) * rs2 * w2.y + b2.y);
      o.y = pk2bf((hi.x - mu2) * rs2 * w2.z + b2.z, (hi.y - mu2) * rs2 * w2.w + b2.w);
      *(uint2*)(BA + row * LDA + l32 * 4) = o;
    }
  }

  // ---------- preload acc2 with xf2 (frees XF as an FF G buffer) ----------
  f32x4 acc2[3][2];
#pragma unroll
  for (int c = 0; c < 2; ++c) {
    const int col0 = (wave + 4 * c) * 16 + kgrp * 4;
#pragma unroll
    for (int xr = 0; xr < 3; ++xr) {
      const uint2 t2 = *(const uint2*)(XF + (xr * 16 + lane16) * LDA + col0);
      const float2 lo = bf2x2(t2.x), hi = bf2x2(t2.y);
      acc2[xr][c][0] = lo.x; acc2[xr][c][1] = lo.y;
      acc2[xr][c][2] = hi.x; acc2[xr][c][3] = hi.y;
    }
  }
  __syncthreads();

  // ---------- FF with G ping-pong {BB, XF}: one barrier per t ----------
  // t0: G[0] = gelu(H @ ff1_0 + b) -> BB
  {
    f32x4 g[3][2] = {};
    gemm48T(BA, wt + 65536, 128, g, wave, lane16, kgrp);
#pragma unroll
    for (int c = 0; c < 2; ++c) {
      const int col0 = (wave + 4 * c) * 16 + kgrp * 4;
      const float4 bv = *(const float4*)(f1b + col0);
#pragma unroll
      for (int xr = 0; xr < 3; ++xr) {
        uint2 o;
        o.x = pk2bf(gelu_f(g[xr][c][0] + bv.x), gelu_f(g[xr][c][1] + bv.y));
        o.y = pk2bf(gelu_f(g[xr][c][2] + bv.z), gelu_f(g[xr][c][3] + bv.w));
        *(uint2*)(BB + (xr * 16 + lane16) * LDA + col0) = o;
      }
    }
  }
  __syncthreads();
#pragma unroll
  for (int t = 1; t < 4; ++t) {
    u16* const Gprev = (t & 1) ? BB : XF;
    u16* const Gcur  = (t & 1) ? XF : BB;
    // acc2 += G[t-1] @ ff2_{t-1}
    gemm48T(Gprev, wt + 131072 + (t - 1) * 128, 512, acc2, wave, lane16, kgrp);
    // G[t] = gelu(H @ ff1_t + b) -> other buffer
    f32x4 g[3][2] = {};
    gemm48T(BA, wt + 65536 + t * 16384, 128, g, wave, lane16, kgrp);
#pragma unroll
    for (int c = 0; c < 2; ++c) {
      const int col0 = (wave + 4 * c) * 16 + kgrp * 4;
      const float4 bv = *(const float4*)(f1b + t * 128 + col0);
#pragma unroll
      for (int xr = 0; xr < 3; ++xr) {
        uint2 o;
        o.x = pk2bf(gelu_f(g[xr][c][0] + bv.x), gelu_f(g[xr][c][1] + bv.y));
        o.y = pk2bf(gelu_f(g[xr][c][2] + bv.z), gelu_f(g[xr][c][3] + bv.w));
        *(uint2*)(Gcur + (xr * 16 + lane16) * LDA + col0) = o;
      }
    }
    __syncthreads();
  }
  // final: acc2 += G[3] @ ff2_3  (G[3] in XF)
  gemm48T(XF, wt + 131072 + 3 * 128, 512, acc2, wave, lane16, kgrp);

  // ---------- out = x + (xf2 + ff_out) + ff2b  (acc2 already holds xf2) ----------
#pragma unroll
  for (int c = 0; c < 2; ++c) {
    const int col0 = (wave + 4 * c) * 16 + kgrp * 4;
    const float4 fb = *(const float4*)(f2b + col0);
#pragma unroll
    for (int xr = 0; xr < 3; ++xr) {
      const int row  = xr * 16 + lane16;
      const int slot = row / 6, ch = row % 6;
      const size_t gi = (size_t)(slot0 + slot) * 768 + ch * 128 + col0;
      const float4 xv = *(const float4*)(x + gi);
      float4 o;
      o.x = xv.x + acc2[xr][c][0] + fb.x;
      o.y = xv.y + acc2[xr][c][1] + fb.y;
      o.z = xv.z + acc2[xr][c][2] + fb.z;
      o.w = xv.w + acc2[xr][c][3] + fb.w;
      *(float4*)(out + gi) = o;
    }
  }
}

extern "C" void kernel_launch(void* const* d_in, const int* in_sizes, int n_in,
                              void* d_out, int out_size, void* d_ws, size_t ws_size,
                              hipStream_t stream) {
  const float* x   = (const float*)d_in[0];
  const float* nw1 = (const float*)d_in[1];
  const float* nb1 = (const float*)d_in[2];
  const float* nw2 = (const float*)d_in[3];
  const float* nb2 = (const float*)d_in[4];
  const float* qw  = (const float*)d_in[5];
  const float* qb  = (const float*)d_in[6];
  const float* kw  = (const float*)d_in[7];
  const float* kb  = (const float*)d_in[8];
  const float* vw  = (const float*)d_in[9];
  const float* vb  = (const float*)d_in[10];
  const float* ow  = (const float*)d_in[11];
  const float* ob  = (const float*)d_in[12];
  const float* f1w = (const float*)d_in[13];
  const float* f1b = (const float*)d_in[14];
  const float* f2w = (const float*)d_in[15];
  const float* f2b = (const float*)d_in[16];
  u16* wt = (u16*)d_ws;   // 196608 u16 = 384 KB

  convert_w<<<768, 256, 0, stream>>>(qw, kw, vw, ow, f1w, f2w, wt);

  const int M = in_sizes[0] / 768;   // 32768 slots
  mitra_main<<<M / SLOTS, 256, 0, stream>>>(x, nw1, nb1, nw2, nb2,
                                            qb, kb, vb, ob, f1b, f2b,
                                            wt, (float*)d_out);
}